// Round 3
// baseline (714.998 us; speedup 1.0000x reference)
//
#include <hip/hip_runtime.h>

// GNN TARnet: h = x*emb -> 2x graph conv -> two prob heads.
// R3: k_head rebuilt for memory-level parallelism: KC=320 (2000 blocks ~ 8/CU),
//     4-deep explicit prefetch of the weight stream, shfl+LDS reduction, 17KB LDS.

constexpr int B = 8, N = 5000, E = 160000, D = 64, H = 128;
constexpr int BN = B * N;           // 40000
constexpr int ND = N * D;           // 320000
constexpr long BND = (long)BN * D;  // 2,560,000
constexpr int KC = 320;             // k-chunk per head block
constexpr int NIT = KC / 8;         // 40 k-iters per thread

__device__ __forceinline__ float elu_f(float x) {
    return x > 0.0f ? x : __expf(x) - 1.0f;
}

// ---------------- CSR build (edges grouped by child) ----------------
__global__ __launch_bounds__(256) void k_count(const int* __restrict__ edges,
                                               int* __restrict__ cnt) {
    int i = blockIdx.x * 256 + threadIdx.x;
    if (i < E) atomicAdd(&cnt[edges[2 * i + 1]], 1);
}

__global__ __launch_bounds__(256) void k_scan(const int* __restrict__ cnt,
                                              int* __restrict__ offs) {
    __shared__ int part[256];
    int t = threadIdx.x;
    const int CH = 20;
    int base = t * CH;
    int s = 0;
    for (int i = 0; i < CH; ++i) { int idx = base + i; if (idx < N) s += cnt[idx]; }
    part[t] = s;
    __syncthreads();
    for (int off = 1; off < 256; off <<= 1) {
        int add = (t >= off) ? part[t - off] : 0;
        __syncthreads();
        part[t] += add;
        __syncthreads();
    }
    int run = part[t] - s;
    for (int i = 0; i < CH; ++i) {
        int idx = base + i;
        if (idx < N) { offs[idx] = run; run += cnt[idx]; }
    }
    if (t == 255) offs[N] = run;
}

__global__ __launch_bounds__(256) void k_fill(const int* __restrict__ edges,
                                              const int* __restrict__ offs,
                                              int* __restrict__ cursor,
                                              int* __restrict__ elist) {
    int i = blockIdx.x * 256 + threadIdx.x;
    if (i < E) {
        int child = edges[2 * i + 1];
        int pos = offs[child] + atomicAdd(&cursor[child], 1);
        elist[pos] = edges[2 * i];
    }
}

// ---------------- prepare: M = elu(elu(h @ W1) @ W2) ----------------
__global__ __launch_bounds__(512) void k_prepare(const float* __restrict__ xsrc,
                                                 const float* __restrict__ emb,
                                                 const float* __restrict__ hin,
                                                 const float* __restrict__ W1,
                                                 const float* __restrict__ W2,
                                                 float* __restrict__ M,
                                                 float* __restrict__ hwt) {
    __shared__ float sW1[64 * 64];      // 16 KB
    __shared__ float sP[128 * 65];      // 33.3 KB
    int t = threadIdx.x;
    int r0 = blockIdx.x * 128;
    for (int i = t; i < 4096; i += 512) sW1[i] = W1[i];
    if (xsrc) {
        for (int i = t; i < 128 * 64; i += 512) {
            int r = i >> 6, c = i & 63;
            int row = r0 + r;
            float v = 0.0f;
            if (row < BN) {
                int n = row % N;
                v = xsrc[row] * emb[n * 64 + c];
                hwt[(long)row * 64 + c] = v;
            }
            sP[r * 65 + c] = v;
        }
    } else {
        for (int i = t; i < 128 * 64; i += 512) {
            int r = i >> 6, c = i & 63;
            int row = r0 + r;
            sP[r * 65 + c] = (row < BN) ? hin[(long)row * 64 + c] : 0.0f;
        }
    }
    __syncthreads();

    int cg = t & 15, rg = t >> 4;
    float acc[4][4] = {};
    #pragma unroll 4
    for (int k = 0; k < 64; ++k) {
        float a[4];
        #pragma unroll
        for (int i = 0; i < 4; ++i) a[i] = sP[(rg * 4 + i) * 65 + k];
        float4 bb = *reinterpret_cast<const float4*>(&sW1[k * 64 + cg * 4]);
        #pragma unroll
        for (int i = 0; i < 4; ++i) {
            acc[i][0] += a[i] * bb.x; acc[i][1] += a[i] * bb.y;
            acc[i][2] += a[i] * bb.z; acc[i][3] += a[i] * bb.w;
        }
    }
    __syncthreads();
    #pragma unroll
    for (int i = 0; i < 4; ++i)
        #pragma unroll
        for (int j = 0; j < 4; ++j)
            sP[(rg * 4 + i) * 65 + cg * 4 + j] = elu_f(acc[i][j]);
    __syncthreads();

    float acc2[4][4] = {};
    #pragma unroll 4
    for (int k = 0; k < 64; ++k) {
        float a[4];
        #pragma unroll
        for (int i = 0; i < 4; ++i) a[i] = sP[(rg * 4 + i) * 65 + k];
        float4 bb = *reinterpret_cast<const float4*>(&W2[k * 64 + cg * 4]);
        #pragma unroll
        for (int i = 0; i < 4; ++i) {
            acc2[i][0] += a[i] * bb.x; acc2[i][1] += a[i] * bb.y;
            acc2[i][2] += a[i] * bb.z; acc2[i][3] += a[i] * bb.w;
        }
    }
    #pragma unroll
    for (int i = 0; i < 4; ++i) {
        int row = r0 + rg * 4 + i;
        if (row < BN) {
            float4 o = make_float4(elu_f(acc2[i][0]), elu_f(acc2[i][1]),
                                   elu_f(acc2[i][2]), elu_f(acc2[i][3]));
            *reinterpret_cast<float4*>(&M[(long)row * 64 + cg * 4]) = o;
        }
    }
}

// ---------------- agg[b,n,:] = sum_{e: child==n} M[b, parent_e, :] ----------------
__global__ __launch_bounds__(256) void k_aggregate(const float* __restrict__ M,
                                                   const int* __restrict__ offs,
                                                   const int* __restrict__ elist,
                                                   float* __restrict__ agg) {
    int t = threadIdx.x;
    int lane = t & 63, wv = t >> 6;
    int bn = blockIdx.x * 4 + wv;
    int b = bn / N;
    int n = bn - b * N;
    int e0 = offs[n], e1 = offs[n + 1];
    const float* Mb = M + (long)b * ND;
    int h4 = lane & 15, le = lane >> 4;
    float4 acc = make_float4(0.f, 0.f, 0.f, 0.f);
    for (int e = e0 + le; e < e1; e += 4) {
        int p = elist[e];
        float4 v = *reinterpret_cast<const float4*>(&Mb[(long)p * 64 + h4 * 4]);
        acc.x += v.x; acc.y += v.y; acc.z += v.z; acc.w += v.w;
    }
    #pragma unroll
    for (int m = 16; m <= 32; m <<= 1) {
        acc.x += __shfl_xor(acc.x, m);
        acc.y += __shfl_xor(acc.y, m);
        acc.z += __shfl_xor(acc.z, m);
        acc.w += __shfl_xor(acc.w, m);
    }
    if (le == 0)
        *reinterpret_cast<float4*>(&agg[(long)bn * 64 + h4 * 4]) = acc;
}

// ---------------- fused update: hout = (elu([h,agg]@W1 + b1)) @ W2 + b2 ----------------
__global__ __launch_bounds__(512) void k_update(const float* __restrict__ h,
                                                const float* __restrict__ agg,
                                                const float* __restrict__ W1,   // [128][64]
                                                const float* __restrict__ b1,
                                                const float* __restrict__ W2,   // [64][64]
                                                const float* __restrict__ b2,
                                                float* __restrict__ hout) {
    __shared__ float sW1[128 * 64];     // 32 KB
    __shared__ float sP[64 * 129];      // 33 KB
    int t = threadIdx.x;
    long r0 = (long)blockIdx.x * 64;
    for (int i = t; i < 128 * 64; i += 512) sW1[i] = W1[i];
    for (int i = t; i < 64 * 128; i += 512) {
        int r = i >> 7, k = i & 127;
        long row = r0 + r;
        float v = (k < 64) ? h[row * 64 + k] : agg[row * 64 + (k - 64)];
        sP[r * 129 + k] = v;
    }
    __syncthreads();

    int cg = t & 15, rg = t >> 4;
    float acc[2][4] = {};
    #pragma unroll 4
    for (int k = 0; k < 128; ++k) {
        float a0 = sP[(rg * 2 + 0) * 129 + k];
        float a1 = sP[(rg * 2 + 1) * 129 + k];
        float4 bb = *reinterpret_cast<const float4*>(&sW1[k * 64 + cg * 4]);
        acc[0][0] += a0 * bb.x; acc[0][1] += a0 * bb.y; acc[0][2] += a0 * bb.z; acc[0][3] += a0 * bb.w;
        acc[1][0] += a1 * bb.x; acc[1][1] += a1 * bb.y; acc[1][2] += a1 * bb.z; acc[1][3] += a1 * bb.w;
    }
    float4 bv1 = *reinterpret_cast<const float4*>(&b1[cg * 4]);
    __syncthreads();
    #pragma unroll
    for (int i = 0; i < 2; ++i) {
        sP[(rg * 2 + i) * 129 + cg * 4 + 0] = elu_f(acc[i][0] + bv1.x);
        sP[(rg * 2 + i) * 129 + cg * 4 + 1] = elu_f(acc[i][1] + bv1.y);
        sP[(rg * 2 + i) * 129 + cg * 4 + 2] = elu_f(acc[i][2] + bv1.z);
        sP[(rg * 2 + i) * 129 + cg * 4 + 3] = elu_f(acc[i][3] + bv1.w);
    }
    __syncthreads();

    float acc2[2][4] = {};
    #pragma unroll 4
    for (int k = 0; k < 64; ++k) {
        float a0 = sP[(rg * 2 + 0) * 129 + k];
        float a1 = sP[(rg * 2 + 1) * 129 + k];
        float4 bb = *reinterpret_cast<const float4*>(&W2[k * 64 + cg * 4]);
        acc2[0][0] += a0 * bb.x; acc2[0][1] += a0 * bb.y; acc2[0][2] += a0 * bb.z; acc2[0][3] += a0 * bb.w;
        acc2[1][0] += a1 * bb.x; acc2[1][1] += a1 * bb.y; acc2[1][2] += a1 * bb.z; acc2[1][3] += a1 * bb.w;
    }
    float4 bv2 = *reinterpret_cast<const float4*>(&b2[cg * 4]);
    #pragma unroll
    for (int i = 0; i < 2; ++i) {
        float4 o = make_float4(acc2[i][0] + bv2.x, acc2[i][1] + bv2.y,
                               acc2[i][2] + bv2.z, acc2[i][3] + bv2.w);
        *reinterpret_cast<float4*>(&hout[(r0 + rg * 2 + i) * 64 + cg * 4]) = o;
    }
}

// ---------------- hidden[head,b,h] = sum_k phi[b,k] * wa[k,h] ----------------
// Streaming GEMV, latency-optimized: 2000 blocks (~8/CU), 4-deep rolling
// prefetch of the 1KB/wave weight stream, phi chunk in LDS (broadcast reads),
// shfl_xor(32) + 4-wave LDS reduction, 1024 atomics/block.
__global__ __launch_bounds__(256) void k_head(const float* __restrict__ phi,   // [8][ND]
                                              const float* __restrict__ w0a,
                                              const float* __restrict__ w1a,
                                              float* __restrict__ hidden) {    // [2][8][H]
    __shared__ float smem[4 * 32 * 33];    // 16.9 KB; phi chunk (8*KC=2560 fl) shares it
    const float* wa = blockIdx.y ? w1a : w0a;
    float* hid = hidden + blockIdx.y * (8 * H);
    int t = threadIdx.x;
    int k0 = blockIdx.x * KC;

    #pragma unroll
    for (int b = 0; b < 8; ++b)
        for (int kk = t; kk < KC; kk += 256)
            smem[b * KC + kk] = phi[(long)b * ND + k0 + kk];
    __syncthreads();

    int w = t >> 6, l = t & 63;
    int h4 = l & 31, kh = l >> 5;
    int kl = w * 2 + kh;                       // [0,8)
    const float* wp = wa + (long)(k0 + kl) * H + h4 * 4;

    float4 acc[8];
    #pragma unroll
    for (int b = 0; b < 8; ++b) acc[b] = make_float4(0.f, 0.f, 0.f, 0.f);
    float4 buf[4];
    #pragma unroll
    for (int j = 0; j < 4; ++j)
        buf[j] = *reinterpret_cast<const float4*>(wp + (long)j * 8 * H);

    for (int g = 0; g < NIT / 4 - 1; ++g) {
        #pragma unroll
        for (int j = 0; j < 4; ++j) {
            float4 w4 = buf[j];
            buf[j] = *reinterpret_cast<const float4*>(wp + (long)((g + 1) * 4 + j) * 8 * H);
            int kk = (g * 4 + j) * 8 + kl;
            #pragma unroll
            for (int b = 0; b < 8; ++b) {
                float p = smem[b * KC + kk];
                acc[b].x += p * w4.x; acc[b].y += p * w4.y;
                acc[b].z += p * w4.z; acc[b].w += p * w4.w;
            }
        }
    }
    {   // epilogue group
        const int g = NIT / 4 - 1;
        #pragma unroll
        for (int j = 0; j < 4; ++j) {
            float4 w4 = buf[j];
            int kk = (g * 4 + j) * 8 + kl;
            #pragma unroll
            for (int b = 0; b < 8; ++b) {
                float p = smem[b * KC + kk];
                acc[b].x += p * w4.x; acc[b].y += p * w4.y;
                acc[b].z += p * w4.z; acc[b].w += p * w4.w;
            }
        }
    }

    // merge the two kh half-waves in-register
    #pragma unroll
    for (int b = 0; b < 8; ++b) {
        acc[b].x += __shfl_xor(acc[b].x, 32);
        acc[b].y += __shfl_xor(acc[b].y, 32);
        acc[b].z += __shfl_xor(acc[b].z, 32);
        acc[b].w += __shfl_xor(acc[b].w, 32);
    }
    __syncthreads();   // phi reads done; smem reused for partials
    if (kh == 0) {
        int base = (w * 32 + h4) * 33;
        #pragma unroll
        for (int b = 0; b < 8; ++b) {
            smem[base + b * 4 + 0] = acc[b].x;
            smem[base + b * 4 + 1] = acc[b].y;
            smem[base + b * 4 + 2] = acc[b].z;
            smem[base + b * 4 + 3] = acc[b].w;
        }
    }
    __syncthreads();

    int h4r = t & 31, br = t >> 5;
    float s0 = 0.f, s1 = 0.f, s2 = 0.f, s3 = 0.f;
    #pragma unroll
    for (int wv = 0; wv < 4; ++wv) {
        int idx = (wv * 32 + h4r) * 33 + br * 4;
        s0 += smem[idx + 0]; s1 += smem[idx + 1];
        s2 += smem[idx + 2]; s3 += smem[idx + 3];
    }
    unsafeAtomicAdd(&hid[br * H + h4r * 4 + 0], s0);
    unsafeAtomicAdd(&hid[br * H + h4r * 4 + 1], s1);
    unsafeAtomicAdd(&hid[br * H + h4r * 4 + 2], s2);
    unsafeAtomicAdd(&hid[br * H + h4r * 4 + 3], s3);
}

// ---------------- out[b, head*2+j] = elu(hidden+ba) @ wb + bb ----------------
__global__ __launch_bounds__(64) void k_final(const float* __restrict__ hidden,
                                              const float* __restrict__ b0a,
                                              const float* __restrict__ w0b,
                                              const float* __restrict__ b0b,
                                              const float* __restrict__ b1a,
                                              const float* __restrict__ w1b,
                                              const float* __restrict__ b1b,
                                              float* __restrict__ out) {
    int t = threadIdx.x;
    if (t >= 32) return;
    int head = t >> 4, b = (t >> 1) & 7, j = t & 1;
    const float* hid = hidden + head * (8 * H) + b * H;
    const float* ba = head ? b1a : b0a;
    const float* wb = head ? w1b : w0b;
    const float* bb = head ? b1b : b0b;
    float acc = 0.0f;
    for (int hh = 0; hh < H; ++hh)
        acc += elu_f(hid[hh] + ba[hh]) * wb[hh * 2 + j];
    out[b * 4 + head * 2 + j] = acc + bb[j];
}

extern "C" void kernel_launch(void* const* d_in, const int* in_sizes, int n_in,
                              void* d_out, int out_size, void* d_ws, size_t ws_size,
                              hipStream_t stream) {
    const float* x      = (const float*)d_in[0];
    const int*   edges  = (const int*)d_in[1];
    const float* emb    = (const float*)d_in[2];
    const float* c1_pw1 = (const float*)d_in[3];
    const float* c1_pw2 = (const float*)d_in[4];
    const float* c1_uw1 = (const float*)d_in[5];
    const float* c1_ub1 = (const float*)d_in[6];
    const float* c1_uw2 = (const float*)d_in[7];
    const float* c1_ub2 = (const float*)d_in[8];
    const float* c2_pw1 = (const float*)d_in[9];
    const float* c2_pw2 = (const float*)d_in[10];
    const float* c2_uw1 = (const float*)d_in[11];
    const float* c2_ub1 = (const float*)d_in[12];
    const float* c2_uw2 = (const float*)d_in[13];
    const float* c2_ub2 = (const float*)d_in[14];
    const float* w0a    = (const float*)d_in[15];
    const float* b0a    = (const float*)d_in[16];
    const float* w0b    = (const float*)d_in[17];
    const float* b0b    = (const float*)d_in[18];
    const float* w1a    = (const float*)d_in[19];
    const float* b1a    = (const float*)d_in[20];
    const float* w1b    = (const float*)d_in[21];
    const float* b1b    = (const float*)d_in[22];
    float* out = (float*)d_out;

    float* hA     = (float*)d_ws;          // [BN, D]
    float* hB     = hA + BND;
    float* Mu     = hB + BND;
    float* agg    = Mu + BND;
    float* hidden = agg + BND;             // [2][8][H] = 2048 floats
    int* cnt      = (int*)(hidden + 2048); // [N]
    int* cursor   = cnt + N;               // [N]
    int* offs     = cursor + N;            // [N+1]
    int* elist    = offs + N + 1;          // [E]

    hipMemsetAsync(hidden, 0, (2048 + 2 * N) * sizeof(float), stream);

    k_count<<<(E + 255) / 256, 256, 0, stream>>>(edges, cnt);
    k_scan<<<1, 256, 0, stream>>>(cnt, offs);
    k_fill<<<(E + 255) / 256, 256, 0, stream>>>(edges, offs, cursor, elist);

    // conv1 (prepare also materializes hA = x*emb)
    k_prepare<<<(BN + 127) / 128, 512, 0, stream>>>(x, emb, nullptr, c1_pw1, c1_pw2, Mu, hA);
    k_aggregate<<<BN / 4, 256, 0, stream>>>(Mu, offs, elist, agg);
    k_update<<<BN / 64, 512, 0, stream>>>(hA, agg, c1_uw1, c1_ub1, c1_uw2, c1_ub2, hB);

    // conv2
    k_prepare<<<(BN + 127) / 128, 512, 0, stream>>>(nullptr, emb, hB, c2_pw1, c2_pw2, Mu, nullptr);
    k_aggregate<<<BN / 4, 256, 0, stream>>>(Mu, offs, elist, agg);
    k_update<<<BN / 64, 512, 0, stream>>>(hB, agg, c2_uw1, c2_ub1, c2_uw2, c2_ub2, hA);

    // heads
    k_head<<<dim3(ND / KC, 2), 256, 0, stream>>>(hA, w0a, w1a, hidden);
    k_final<<<1, 64, 0, stream>>>(hidden, b0a, w0b, b0b, b1a, w1b, b1b, out);
}

// Round 4
// 616.653 us; speedup vs baseline: 1.1595x; 1.1595x over previous
//
#include <hip/hip_runtime.h>

// GNN TARnet: h = x*emb -> 2x graph conv -> two prob heads.
// R4: k_head atomic-free — per-block partials via coalesced float4 stores
//     (aliasing dead Mu scratch) + 2-level k_reduce. Hot loop identical to R3
//     to cleanly test the "device atomics to hot 8KB region serialize" theory.

constexpr int B = 8, N = 5000, E = 160000, D = 64, H = 128;
constexpr int BN = B * N;           // 40000
constexpr int ND = N * D;           // 320000
constexpr long BND = (long)BN * D;  // 2,560,000
constexpr int KC = 320;             // k-chunk per head block
constexpr int NIT = KC / 8;         // 40 k-iters per thread
constexpr int XB = ND / KC;         // 1000 x-blocks per head

__device__ __forceinline__ float elu_f(float x) {
    return x > 0.0f ? x : __expf(x) - 1.0f;
}

// ---------------- CSR build (edges grouped by child) ----------------
__global__ __launch_bounds__(256) void k_count(const int* __restrict__ edges,
                                               int* __restrict__ cnt) {
    int i = blockIdx.x * 256 + threadIdx.x;
    if (i < E) atomicAdd(&cnt[edges[2 * i + 1]], 1);
}

__global__ __launch_bounds__(256) void k_scan(const int* __restrict__ cnt,
                                              int* __restrict__ offs) {
    __shared__ int part[256];
    int t = threadIdx.x;
    const int CH = 20;
    int base = t * CH;
    int s = 0;
    for (int i = 0; i < CH; ++i) { int idx = base + i; if (idx < N) s += cnt[idx]; }
    part[t] = s;
    __syncthreads();
    for (int off = 1; off < 256; off <<= 1) {
        int add = (t >= off) ? part[t - off] : 0;
        __syncthreads();
        part[t] += add;
        __syncthreads();
    }
    int run = part[t] - s;
    for (int i = 0; i < CH; ++i) {
        int idx = base + i;
        if (idx < N) { offs[idx] = run; run += cnt[idx]; }
    }
    if (t == 255) offs[N] = run;
}

__global__ __launch_bounds__(256) void k_fill(const int* __restrict__ edges,
                                              const int* __restrict__ offs,
                                              int* __restrict__ cursor,
                                              int* __restrict__ elist) {
    int i = blockIdx.x * 256 + threadIdx.x;
    if (i < E) {
        int child = edges[2 * i + 1];
        int pos = offs[child] + atomicAdd(&cursor[child], 1);
        elist[pos] = edges[2 * i];
    }
}

// ---------------- prepare: M = elu(elu(h @ W1) @ W2) ----------------
__global__ __launch_bounds__(512) void k_prepare(const float* __restrict__ xsrc,
                                                 const float* __restrict__ emb,
                                                 const float* __restrict__ hin,
                                                 const float* __restrict__ W1,
                                                 const float* __restrict__ W2,
                                                 float* __restrict__ M,
                                                 float* __restrict__ hwt) {
    __shared__ float sW1[64 * 64];      // 16 KB
    __shared__ float sP[128 * 65];      // 33.3 KB
    int t = threadIdx.x;
    int r0 = blockIdx.x * 128;
    for (int i = t; i < 4096; i += 512) sW1[i] = W1[i];
    if (xsrc) {
        for (int i = t; i < 128 * 64; i += 512) {
            int r = i >> 6, c = i & 63;
            int row = r0 + r;
            float v = 0.0f;
            if (row < BN) {
                int n = row % N;
                v = xsrc[row] * emb[n * 64 + c];
                hwt[(long)row * 64 + c] = v;
            }
            sP[r * 65 + c] = v;
        }
    } else {
        for (int i = t; i < 128 * 64; i += 512) {
            int r = i >> 6, c = i & 63;
            int row = r0 + r;
            sP[r * 65 + c] = (row < BN) ? hin[(long)row * 64 + c] : 0.0f;
        }
    }
    __syncthreads();

    int cg = t & 15, rg = t >> 4;
    float acc[4][4] = {};
    #pragma unroll 4
    for (int k = 0; k < 64; ++k) {
        float a[4];
        #pragma unroll
        for (int i = 0; i < 4; ++i) a[i] = sP[(rg * 4 + i) * 65 + k];
        float4 bb = *reinterpret_cast<const float4*>(&sW1[k * 64 + cg * 4]);
        #pragma unroll
        for (int i = 0; i < 4; ++i) {
            acc[i][0] += a[i] * bb.x; acc[i][1] += a[i] * bb.y;
            acc[i][2] += a[i] * bb.z; acc[i][3] += a[i] * bb.w;
        }
    }
    __syncthreads();
    #pragma unroll
    for (int i = 0; i < 4; ++i)
        #pragma unroll
        for (int j = 0; j < 4; ++j)
            sP[(rg * 4 + i) * 65 + cg * 4 + j] = elu_f(acc[i][j]);
    __syncthreads();

    float acc2[4][4] = {};
    #pragma unroll 4
    for (int k = 0; k < 64; ++k) {
        float a[4];
        #pragma unroll
        for (int i = 0; i < 4; ++i) a[i] = sP[(rg * 4 + i) * 65 + k];
        float4 bb = *reinterpret_cast<const float4*>(&W2[k * 64 + cg * 4]);
        #pragma unroll
        for (int i = 0; i < 4; ++i) {
            acc2[i][0] += a[i] * bb.x; acc2[i][1] += a[i] * bb.y;
            acc2[i][2] += a[i] * bb.z; acc2[i][3] += a[i] * bb.w;
        }
    }
    #pragma unroll
    for (int i = 0; i < 4; ++i) {
        int row = r0 + rg * 4 + i;
        if (row < BN) {
            float4 o = make_float4(elu_f(acc2[i][0]), elu_f(acc2[i][1]),
                                   elu_f(acc2[i][2]), elu_f(acc2[i][3]));
            *reinterpret_cast<float4*>(&M[(long)row * 64 + cg * 4]) = o;
        }
    }
}

// ---------------- agg[b,n,:] = sum_{e: child==n} M[b, parent_e, :] ----------------
__global__ __launch_bounds__(256) void k_aggregate(const float* __restrict__ M,
                                                   const int* __restrict__ offs,
                                                   const int* __restrict__ elist,
                                                   float* __restrict__ agg) {
    int t = threadIdx.x;
    int lane = t & 63, wv = t >> 6;
    int bn = blockIdx.x * 4 + wv;
    int b = bn / N;
    int n = bn - b * N;
    int e0 = offs[n], e1 = offs[n + 1];
    const float* Mb = M + (long)b * ND;
    int h4 = lane & 15, le = lane >> 4;
    float4 acc = make_float4(0.f, 0.f, 0.f, 0.f);
    for (int e = e0 + le; e < e1; e += 4) {
        int p = elist[e];
        float4 v = *reinterpret_cast<const float4*>(&Mb[(long)p * 64 + h4 * 4]);
        acc.x += v.x; acc.y += v.y; acc.z += v.z; acc.w += v.w;
    }
    #pragma unroll
    for (int m = 16; m <= 32; m <<= 1) {
        acc.x += __shfl_xor(acc.x, m);
        acc.y += __shfl_xor(acc.y, m);
        acc.z += __shfl_xor(acc.z, m);
        acc.w += __shfl_xor(acc.w, m);
    }
    if (le == 0)
        *reinterpret_cast<float4*>(&agg[(long)bn * 64 + h4 * 4]) = acc;
}

// ---------------- fused update: hout = (elu([h,agg]@W1 + b1)) @ W2 + b2 ----------------
__global__ __launch_bounds__(512) void k_update(const float* __restrict__ h,
                                                const float* __restrict__ agg,
                                                const float* __restrict__ W1,   // [128][64]
                                                const float* __restrict__ b1,
                                                const float* __restrict__ W2,   // [64][64]
                                                const float* __restrict__ b2,
                                                float* __restrict__ hout) {
    __shared__ float sW1[128 * 64];     // 32 KB
    __shared__ float sP[64 * 129];      // 33 KB
    int t = threadIdx.x;
    long r0 = (long)blockIdx.x * 64;
    for (int i = t; i < 128 * 64; i += 512) sW1[i] = W1[i];
    for (int i = t; i < 64 * 128; i += 512) {
        int r = i >> 7, k = i & 127;
        long row = r0 + r;
        float v = (k < 64) ? h[row * 64 + k] : agg[row * 64 + (k - 64)];
        sP[r * 129 + k] = v;
    }
    __syncthreads();

    int cg = t & 15, rg = t >> 4;
    float acc[2][4] = {};
    #pragma unroll 4
    for (int k = 0; k < 128; ++k) {
        float a0 = sP[(rg * 2 + 0) * 129 + k];
        float a1 = sP[(rg * 2 + 1) * 129 + k];
        float4 bb = *reinterpret_cast<const float4*>(&sW1[k * 64 + cg * 4]);
        acc[0][0] += a0 * bb.x; acc[0][1] += a0 * bb.y; acc[0][2] += a0 * bb.z; acc[0][3] += a0 * bb.w;
        acc[1][0] += a1 * bb.x; acc[1][1] += a1 * bb.y; acc[1][2] += a1 * bb.z; acc[1][3] += a1 * bb.w;
    }
    float4 bv1 = *reinterpret_cast<const float4*>(&b1[cg * 4]);
    __syncthreads();
    #pragma unroll
    for (int i = 0; i < 2; ++i) {
        sP[(rg * 2 + i) * 129 + cg * 4 + 0] = elu_f(acc[i][0] + bv1.x);
        sP[(rg * 2 + i) * 129 + cg * 4 + 1] = elu_f(acc[i][1] + bv1.y);
        sP[(rg * 2 + i) * 129 + cg * 4 + 2] = elu_f(acc[i][2] + bv1.z);
        sP[(rg * 2 + i) * 129 + cg * 4 + 3] = elu_f(acc[i][3] + bv1.w);
    }
    __syncthreads();

    float acc2[2][4] = {};
    #pragma unroll 4
    for (int k = 0; k < 64; ++k) {
        float a0 = sP[(rg * 2 + 0) * 129 + k];
        float a1 = sP[(rg * 2 + 1) * 129 + k];
        float4 bb = *reinterpret_cast<const float4*>(&W2[k * 64 + cg * 4]);
        acc2[0][0] += a0 * bb.x; acc2[0][1] += a0 * bb.y; acc2[0][2] += a0 * bb.z; acc2[0][3] += a0 * bb.w;
        acc2[1][0] += a1 * bb.x; acc2[1][1] += a1 * bb.y; acc2[1][2] += a1 * bb.z; acc2[1][3] += a1 * bb.w;
    }
    float4 bv2 = *reinterpret_cast<const float4*>(&b2[cg * 4]);
    #pragma unroll
    for (int i = 0; i < 2; ++i) {
        float4 o = make_float4(acc2[i][0] + bv2.x, acc2[i][1] + bv2.y,
                               acc2[i][2] + bv2.z, acc2[i][3] + bv2.w);
        *reinterpret_cast<float4*>(&hout[(r0 + rg * 2 + i) * 64 + cg * 4]) = o;
    }
}

// ---------------- partial[yb,xb,:] = per-block head GEMV partial ----------------
// Hot loop identical to R3; tail now writes coalesced float4 partials (NO atomics).
__global__ __launch_bounds__(256) void k_head(const float* __restrict__ phi,   // [8][ND]
                                              const float* __restrict__ w0a,
                                              const float* __restrict__ w1a,
                                              float* __restrict__ part) {      // [2][XB][1024]
    __shared__ float smem[4 * 32 * 33];    // 16.9 KB; phi chunk (8*KC=2560 fl) shares it
    const float* wa = blockIdx.y ? w1a : w0a;
    int t = threadIdx.x;
    int k0 = blockIdx.x * KC;

    #pragma unroll
    for (int b = 0; b < 8; ++b)
        for (int kk = t; kk < KC; kk += 256)
            smem[b * KC + kk] = phi[(long)b * ND + k0 + kk];
    __syncthreads();

    int w = t >> 6, l = t & 63;
    int h4 = l & 31, kh = l >> 5;
    int kl = w * 2 + kh;                       // [0,8)
    const float* wp = wa + (long)(k0 + kl) * H + h4 * 4;

    float4 acc[8];
    #pragma unroll
    for (int b = 0; b < 8; ++b) acc[b] = make_float4(0.f, 0.f, 0.f, 0.f);
    float4 buf[4];
    #pragma unroll
    for (int j = 0; j < 4; ++j)
        buf[j] = *reinterpret_cast<const float4*>(wp + (long)j * 8 * H);

    for (int g = 0; g < NIT / 4 - 1; ++g) {
        #pragma unroll
        for (int j = 0; j < 4; ++j) {
            float4 w4 = buf[j];
            buf[j] = *reinterpret_cast<const float4*>(wp + (long)((g + 1) * 4 + j) * 8 * H);
            int kk = (g * 4 + j) * 8 + kl;
            #pragma unroll
            for (int b = 0; b < 8; ++b) {
                float p = smem[b * KC + kk];
                acc[b].x += p * w4.x; acc[b].y += p * w4.y;
                acc[b].z += p * w4.z; acc[b].w += p * w4.w;
            }
        }
    }
    {   // epilogue group
        const int g = NIT / 4 - 1;
        #pragma unroll
        for (int j = 0; j < 4; ++j) {
            float4 w4 = buf[j];
            int kk = (g * 4 + j) * 8 + kl;
            #pragma unroll
            for (int b = 0; b < 8; ++b) {
                float p = smem[b * KC + kk];
                acc[b].x += p * w4.x; acc[b].y += p * w4.y;
                acc[b].z += p * w4.z; acc[b].w += p * w4.w;
            }
        }
    }

    // merge the two kh half-waves in-register
    #pragma unroll
    for (int b = 0; b < 8; ++b) {
        acc[b].x += __shfl_xor(acc[b].x, 32);
        acc[b].y += __shfl_xor(acc[b].y, 32);
        acc[b].z += __shfl_xor(acc[b].z, 32);
        acc[b].w += __shfl_xor(acc[b].w, 32);
    }
    __syncthreads();   // phi reads done; smem reused for partials
    if (kh == 0) {
        int base = (w * 32 + h4) * 33;
        #pragma unroll
        for (int b = 0; b < 8; ++b) {
            smem[base + b * 4 + 0] = acc[b].x;
            smem[base + b * 4 + 1] = acc[b].y;
            smem[base + b * 4 + 2] = acc[b].z;
            smem[base + b * 4 + 3] = acc[b].w;
        }
    }
    __syncthreads();

    int h4r = t & 31, br = t >> 5;
    float s0 = 0.f, s1 = 0.f, s2 = 0.f, s3 = 0.f;
    #pragma unroll
    for (int wv = 0; wv < 4; ++wv) {
        int idx = (wv * 32 + h4r) * 33 + br * 4;
        s0 += smem[idx + 0]; s1 += smem[idx + 1];
        s2 += smem[idx + 2]; s3 += smem[idx + 3];
    }
    float* pb = part + ((long)blockIdx.y * XB + blockIdx.x) * 1024;
    *reinterpret_cast<float4*>(&pb[br * H + h4r * 4]) =
        make_float4(s0, s1, s2, s3);
}

// ---------------- hidden[y*1024+j] = sum_x part[y,x,j] ----------------
// grid (8, 16): 2048 outputs x 16 x-chunks; coalesced column sums; 32K spread atomics.
__global__ __launch_bounds__(256) void k_reduce(const float* __restrict__ part,
                                                float* __restrict__ hidden) {
    int idx = blockIdx.x * 256 + threadIdx.x;      // [0, 2048)
    int c = blockIdx.y;                            // [0, 16)
    int y = idx >> 10, j = idx & 1023;
    const float* p = part + (long)y * XB * 1024 + j;
    int x0 = (XB * c) >> 4, x1 = (XB * (c + 1)) >> 4;
    float s0 = 0.f, s1 = 0.f, s2 = 0.f, s3 = 0.f;
    int x = x0;
    for (; x + 3 < x1; x += 4) {
        s0 += p[(long)(x + 0) * 1024];
        s1 += p[(long)(x + 1) * 1024];
        s2 += p[(long)(x + 2) * 1024];
        s3 += p[(long)(x + 3) * 1024];
    }
    for (; x < x1; ++x) s0 += p[(long)x * 1024];
    unsafeAtomicAdd(&hidden[y * 1024 + j], s0 + s1 + s2 + s3);
}

// ---------------- out[b, head*2+j] = elu(hidden+ba) @ wb + bb ----------------
__global__ __launch_bounds__(64) void k_final(const float* __restrict__ hidden,
                                              const float* __restrict__ b0a,
                                              const float* __restrict__ w0b,
                                              const float* __restrict__ b0b,
                                              const float* __restrict__ b1a,
                                              const float* __restrict__ w1b,
                                              const float* __restrict__ b1b,
                                              float* __restrict__ out) {
    int t = threadIdx.x;
    if (t >= 32) return;
    int head = t >> 4, b = (t >> 1) & 7, j = t & 1;
    const float* hid = hidden + head * (8 * H) + b * H;
    const float* ba = head ? b1a : b0a;
    const float* wb = head ? w1b : w0b;
    const float* bb = head ? b1b : b0b;
    float acc = 0.0f;
    for (int hh = 0; hh < H; ++hh)
        acc += elu_f(hid[hh] + ba[hh]) * wb[hh * 2 + j];
    out[b * 4 + head * 2 + j] = acc + bb[j];
}

extern "C" void kernel_launch(void* const* d_in, const int* in_sizes, int n_in,
                              void* d_out, int out_size, void* d_ws, size_t ws_size,
                              hipStream_t stream) {
    const float* x      = (const float*)d_in[0];
    const int*   edges  = (const int*)d_in[1];
    const float* emb    = (const float*)d_in[2];
    const float* c1_pw1 = (const float*)d_in[3];
    const float* c1_pw2 = (const float*)d_in[4];
    const float* c1_uw1 = (const float*)d_in[5];
    const float* c1_ub1 = (const float*)d_in[6];
    const float* c1_uw2 = (const float*)d_in[7];
    const float* c1_ub2 = (const float*)d_in[8];
    const float* c2_pw1 = (const float*)d_in[9];
    const float* c2_pw2 = (const float*)d_in[10];
    const float* c2_uw1 = (const float*)d_in[11];
    const float* c2_ub1 = (const float*)d_in[12];
    const float* c2_uw2 = (const float*)d_in[13];
    const float* c2_ub2 = (const float*)d_in[14];
    const float* w0a    = (const float*)d_in[15];
    const float* b0a    = (const float*)d_in[16];
    const float* w0b    = (const float*)d_in[17];
    const float* b0b    = (const float*)d_in[18];
    const float* w1a    = (const float*)d_in[19];
    const float* b1a    = (const float*)d_in[20];
    const float* w1b    = (const float*)d_in[21];
    const float* b1b    = (const float*)d_in[22];
    float* out = (float*)d_out;

    float* hA     = (float*)d_ws;          // [BN, D]
    float* hB     = hA + BND;
    float* Mu     = hB + BND;              // also aliased as `part` for k_head
    float* agg    = Mu + BND;
    float* hidden = agg + BND;             // [2][8][H] = 2048 floats
    int* cnt      = (int*)(hidden + 2048); // [N]
    int* cursor   = cnt + N;               // [N]
    int* offs     = cursor + N;            // [N+1]
    int* elist    = offs + N + 1;          // [E]
    float* part   = Mu;                    // [2][XB][1024] = 2.048M floats <= BND

    hipMemsetAsync(hidden, 0, (2048 + 2 * N) * sizeof(float), stream);

    k_count<<<(E + 255) / 256, 256, 0, stream>>>(edges, cnt);
    k_scan<<<1, 256, 0, stream>>>(cnt, offs);
    k_fill<<<(E + 255) / 256, 256, 0, stream>>>(edges, offs, cursor, elist);

    // conv1 (prepare also materializes hA = x*emb)
    k_prepare<<<(BN + 127) / 128, 512, 0, stream>>>(x, emb, nullptr, c1_pw1, c1_pw2, Mu, hA);
    k_aggregate<<<BN / 4, 256, 0, stream>>>(Mu, offs, elist, agg);
    k_update<<<BN / 64, 512, 0, stream>>>(hA, agg, c1_uw1, c1_ub1, c1_uw2, c1_ub2, hB);

    // conv2
    k_prepare<<<(BN + 127) / 128, 512, 0, stream>>>(nullptr, emb, hB, c2_pw1, c2_pw2, Mu, nullptr);
    k_aggregate<<<BN / 4, 256, 0, stream>>>(Mu, offs, elist, agg);
    k_update<<<BN / 64, 512, 0, stream>>>(hB, agg, c2_uw1, c2_ub1, c2_uw2, c2_ub2, hA);

    // heads: partials (Mu is dead scratch by now) -> reduce -> final
    k_head<<<dim3(XB, 2), 256, 0, stream>>>(hA, w0a, w1a, part);
    k_reduce<<<dim3(8, 16), 256, 0, stream>>>(part, hidden);
    k_final<<<1, 64, 0, stream>>>(hidden, b0a, w0b, b0b, b1a, w1b, b1b, out);
}